// Round 2
// baseline (357.896 us; speedup 1.0000x reference)
//
#include <hip/hip_runtime.h>
#include <hip/hip_bf16.h>
#include <stdint.h>

typedef unsigned short u16;
typedef __bf16 bf16_t;
typedef bf16_t bf16x8 __attribute__((ext_vector_type(8)));
typedef float f32x4 __attribute__((ext_vector_type(4)));

#define NTOK 32768
#define CEMB 256
#define NHEAD 8
#define HD 32
#define BSEG 128
#define TSEG 256

static __device__ __forceinline__ bf16x8 ld16(const u16* p) {
  uint4 v = *reinterpret_cast<const uint4*>(p);
  return __builtin_bit_cast(bf16x8, v);
}
static __device__ __forceinline__ u16 f2b(float f) {
  return __builtin_bit_cast(u16, (bf16_t)f);
}

// ---------------- K0: convert x and weights to bf16 ----------------
__global__ void k_convert(const float* __restrict__ x,
                          const float* __restrict__ wq, const float* __restrict__ wk,
                          const float* __restrict__ wv, const float* __restrict__ wp,
                          u16* __restrict__ xb, u16* __restrict__ wb) {
  const int XSLOTS = (NTOK * CEMB) / 8;      // 1048576
  const int WSLOTS = (4 * CEMB * CEMB) / 8;  // 32768
  int slot = blockIdx.x * blockDim.x + threadIdx.x;
  if (slot >= XSLOTS + WSLOTS) return;
  const float* src;
  u16* dst;
  if (slot < XSLOTS) {
    src = x + slot * 8;
    dst = xb + slot * 8;
  } else {
    int e = (slot - XSLOTS) * 8;
    int wsel = e >> 16, off = e & 65535;
    const float* s0 = (wsel == 0) ? wq : ((wsel == 1) ? wk : ((wsel == 2) ? wv : wp));
    src = s0 + off;
    dst = wb + e;
  }
  float4 a = reinterpret_cast<const float4*>(src)[0];
  float4 b = reinterpret_cast<const float4*>(src)[1];
  u16 o[8] = {f2b(a.x), f2b(a.y), f2b(a.z), f2b(a.w),
              f2b(b.x), f2b(b.y), f2b(b.z), f2b(b.w)};
  *reinterpret_cast<uint4*>(dst) = *reinterpret_cast<const uint4*>(o);
}

// ---------------- K1: QKV projection GEMMs ----------------
__global__ __launch_bounds__(256, 4)
void k_qkv(const u16* __restrict__ xb, const u16* __restrict__ wb,
           const float* __restrict__ bq, const float* __restrict__ bk,
           const float* __restrict__ bv,
           u16* __restrict__ q_ws, u16* __restrict__ k_ws, u16* __restrict__ v_ws) {
  const int mode = blockIdx.z;
  const int m0 = blockIdx.x * 128;
  const int n0 = blockIdx.y * 64;
  const int tid = threadIdx.x;
  const int w = tid >> 6, l = tid & 63;
  const int lr = l & 15, lg = l >> 4;
  __shared__ u16 Ts[64][136];  // V-transpose bounce buffer

  const u16* W = wb + mode * (CEMB * CEMB);
  const float* bias = (mode == 0) ? bq : ((mode == 1) ? bk : bv);

  f32x4 acc[2][4];
#pragma unroll
  for (int mf = 0; mf < 2; ++mf)
#pragma unroll
    for (int nf = 0; nf < 4; ++nf) {
      f32x4 z = {0.f, 0.f, 0.f, 0.f};
      acc[mf][nf] = z;
    }
  const int mrow = m0 + w * 32;

#pragma unroll
  for (int kt = 0; kt < 4; ++kt) {
    bf16x8 af[2][2];
#pragma unroll
    for (int mf = 0; mf < 2; ++mf)
#pragma unroll
      for (int kk = 0; kk < 2; ++kk)
        af[mf][kk] = ld16(xb + (mrow + mf * 16 + lr) * CEMB + kt * 64 + kk * 32 + lg * 8);
#pragma unroll
    for (int nf = 0; nf < 4; ++nf) {
#pragma unroll
      for (int kk = 0; kk < 2; ++kk) {
        bf16x8 bfrag = ld16(W + (n0 + nf * 16 + lr) * CEMB + kt * 64 + kk * 32 + lg * 8);
#pragma unroll
        for (int mf = 0; mf < 2; ++mf)
          acc[mf][nf] = __builtin_amdgcn_mfma_f32_16x16x32_bf16(af[mf][kk], bfrag, acc[mf][nf], 0, 0, 0);
      }
    }
  }

  float bb[4];
#pragma unroll
  for (int nf = 0; nf < 4; ++nf) bb[nf] = bias[n0 + nf * 16 + lr];

  if (mode < 2) {
    u16* out = (mode == 0) ? q_ws : k_ws;
#pragma unroll
    for (int mf = 0; mf < 2; ++mf)
#pragma unroll
      for (int nf = 0; nf < 4; ++nf)
#pragma unroll
        for (int r = 0; r < 4; ++r) {
          int m = mrow + mf * 16 + lg * 4 + r;
          int c = n0 + nf * 16 + lr;
          int bs = m >> 8, t = m & 255, hh = c >> 5, d = c & 31;
          out[((bs * NHEAD + hh) * TSEG + t) * HD + d] = f2b(acc[mf][nf][r] + bb[nf]);
        }
  } else {
    // stage into LDS then store V transposed: v_ws[(b*8+h)*32+d][t]
#pragma unroll
    for (int mf = 0; mf < 2; ++mf)
#pragma unroll
      for (int nf = 0; nf < 4; ++nf)
#pragma unroll
        for (int r = 0; r < 4; ++r)
          Ts[nf * 16 + lr][w * 32 + mf * 16 + lg * 4 + r] = f2b(acc[mf][nf][r] + bb[nf]);
    __syncthreads();
    int row = tid >> 2;            // 0..63 : local c
    int seg = (tid & 3) * 32;      // t offset chunk
    int c = n0 + row, hh = c >> 5, d = c & 31;
    int bs = m0 >> 8, t0 = m0 & 255;
    u16* dst = v_ws + ((bs * NHEAD + hh) * HD + d) * TSEG + t0 + seg;
#pragma unroll
    for (int j = 0; j < 4; ++j)
      reinterpret_cast<uint4*>(dst)[j] = *reinterpret_cast<const uint4*>(&Ts[row][seg + j * 8]);
  }
}

// ---------------- K2: attention ----------------
// Block = (tq-tile of 16 rows, b). 4 waves; wave w handles heads 2w, 2w+1.
// S^T = mfma(A=K(permuted rows), B=Q): lane (lr,lg) ends up holding
// P^T[s = K2*32 + 8*lg + e][t = tbase+lr] for e=0..7 -> PV B-fragments are
// pure in-register bf16 packing (no LDS, no shuffles).
__global__ __launch_bounds__(256, 3)
void k_attn(const u16* __restrict__ q_ws, const u16* __restrict__ k_ws,
            const u16* __restrict__ v_ws,
            u16* __restrict__ y_ws, float* __restrict__ mean_out) {
  const int b = blockIdx.y;
  const int tbase = blockIdx.x * 16;
  const int tid = threadIdx.x;
  const int w = tid >> 6, l = tid & 63;
  const int lr = l & 15, lg = l >> 4;

  __shared__ float smean[TSEG * 17];  // transposed [s][t], stride 17 (bank-friendly)

  for (int i = tid; i < TSEG * 17; i += 256) smean[i] = 0.f;
  __syncthreads();

  float macc[16][4];
#pragma unroll
  for (int st = 0; st < 16; ++st)
#pragma unroll
    for (int r = 0; r < 4; ++r) macc[st][r] = 0.f;

  const float sc = 0.17677669529663687f * 1.4426950408889634f;  // 1/sqrt(32) * log2(e)
  const int rowperm = 8 * (lr >> 2) + (lr & 3);

  for (int hi = 0; hi < 2; ++hi) {
    const int h = w * 2 + hi;
    const u16* qh = q_ws + (b * NHEAD + h) * TSEG * HD;
    const u16* kh = k_ws + (b * NHEAD + h) * TSEG * HD;
    const u16* vh = v_ws + (b * NHEAD + h) * HD * TSEG;

    bf16x8 qf = ld16(qh + (tbase + lr) * HD + lg * 8);

    // QK^T (transposed): 16 s-tiles, K rows permuted so D-values are
    // lane-local contiguous in s for the PV B-fragment.
    float s[16][4];
#pragma unroll
    for (int st = 0; st < 16; ++st) {
      int srow = (st >> 1) * 32 + (st & 1) * 4 + rowperm;
      bf16x8 kf = ld16(kh + srow * HD + lg * 8);
      f32x4 z = {0.f, 0.f, 0.f, 0.f};
      f32x4 d = __builtin_amdgcn_mfma_f32_16x16x32_bf16(kf, qf, z, 0, 0, 0);
#pragma unroll
      for (int r = 0; r < 4; ++r) s[st][r] = d[r] * sc;
    }

    // softmax over s for fixed t=lr: in-lane 64 values + reduce over lg groups
    float mx = s[0][0];
#pragma unroll
    for (int st = 0; st < 16; ++st)
#pragma unroll
      for (int r = 0; r < 4; ++r) mx = fmaxf(mx, s[st][r]);
    mx = fmaxf(mx, __shfl_xor(mx, 16, 64));
    mx = fmaxf(mx, __shfl_xor(mx, 32, 64));

    float sm = 0.f;
#pragma unroll
    for (int st = 0; st < 16; ++st)
#pragma unroll
      for (int r = 0; r < 4; ++r) {
        float p = exp2f(s[st][r] - mx);
        s[st][r] = p;
        sm += p;
      }
    sm += __shfl_xor(sm, 16, 64);
    sm += __shfl_xor(sm, 32, 64);
    float inv = __builtin_amdgcn_rcpf(sm);

    // normalize, accumulate mean, pack PV B-fragments in-register
    bf16x8 pb[8];
#pragma unroll
    for (int kk = 0; kk < 8; ++kk)
#pragma unroll
      for (int e = 0; e < 4; ++e) {
        float p0 = s[2 * kk][e] * inv;
        float p1 = s[2 * kk + 1][e] * inv;
        macc[2 * kk][e] += p0;
        macc[2 * kk + 1][e] += p1;
        pb[kk][e] = (bf16_t)p0;
        pb[kk][4 + e] = (bf16_t)p1;
      }

    // PV: y^T[d][t] = sum_s V^T[d][s] P^T[s][t]
#pragma unroll
    for (int dt = 0; dt < 2; ++dt) {
      f32x4 y = {0.f, 0.f, 0.f, 0.f};
#pragma unroll
      for (int kk = 0; kk < 8; ++kk) {
        bf16x8 vf = ld16(vh + (dt * 16 + lr) * TSEG + kk * 32 + lg * 8);
        y = __builtin_amdgcn_mfma_f32_16x16x32_bf16(vf, pb[kk], y, 0, 0, 0);
      }
      u16 o[4] = {f2b(y[0]), f2b(y[1]), f2b(y[2]), f2b(y[3])};
      *reinterpret_cast<uint2*>(
          y_ws + (size_t)(b * TSEG + tbase + lr) * CEMB + h * HD + dt * 16 + lg * 4) =
          *reinterpret_cast<const uint2*>(o);
    }
  }

  // cross-wave head reduction for attn mean: smean[s][t] += macc
#pragma unroll
  for (int st = 0; st < 16; ++st) {
    int sbase = (st >> 1) * 32 + (st & 1) * 4 + 8 * lg;
#pragma unroll
    for (int r = 0; r < 4; ++r)
      atomicAdd(&smean[(sbase + r) * 17 + lr], macc[st][r]);
  }
  __syncthreads();

  // write mean_out[b, tbase+trow, :] (f32, /NHEAD)
  {
    int trow = tid >> 4;            // 0..15
    int sc0 = (tid & 15) * 16;      // s chunk base
    float* dst = mean_out + (size_t)(b * TSEG + tbase + trow) * TSEG + sc0;
#pragma unroll
    for (int j = 0; j < 4; ++j) {
      float4 v;
      v.x = smean[(sc0 + j * 4 + 0) * 17 + trow];
      v.y = smean[(sc0 + j * 4 + 1) * 17 + trow];
      v.z = smean[(sc0 + j * 4 + 2) * 17 + trow];
      v.w = smean[(sc0 + j * 4 + 3) * 17 + trow];
      v.x *= 0.125f; v.y *= 0.125f; v.z *= 0.125f; v.w *= 0.125f;
      *reinterpret_cast<float4*>(dst + j * 4) = v;
    }
  }
}

// ---------------- K3: output projection ----------------
__global__ __launch_bounds__(256, 4)
void k_proj(const u16* __restrict__ yb, const u16* __restrict__ wb,
            const float* __restrict__ bp, float* __restrict__ out) {
  const int m0 = blockIdx.x * 128;
  const int n0 = blockIdx.y * 64;
  const int tid = threadIdx.x;
  const int w = tid >> 6, l = tid & 63;
  const int lr = l & 15, lg = l >> 4;
  const u16* W = wb + 3 * (CEMB * CEMB);

  f32x4 acc[2][4];
#pragma unroll
  for (int mf = 0; mf < 2; ++mf)
#pragma unroll
    for (int nf = 0; nf < 4; ++nf) {
      f32x4 z = {0.f, 0.f, 0.f, 0.f};
      acc[mf][nf] = z;
    }
  const int mrow = m0 + w * 32;

#pragma unroll
  for (int kt = 0; kt < 4; ++kt) {
    bf16x8 af[2][2];
#pragma unroll
    for (int mf = 0; mf < 2; ++mf)
#pragma unroll
      for (int kk = 0; kk < 2; ++kk)
        af[mf][kk] = ld16(yb + (mrow + mf * 16 + lr) * CEMB + kt * 64 + kk * 32 + lg * 8);
#pragma unroll
    for (int nf = 0; nf < 4; ++nf) {
#pragma unroll
      for (int kk = 0; kk < 2; ++kk) {
        bf16x8 bfrag = ld16(W + (n0 + nf * 16 + lr) * CEMB + kt * 64 + kk * 32 + lg * 8);
#pragma unroll
        for (int mf = 0; mf < 2; ++mf)
          acc[mf][nf] = __builtin_amdgcn_mfma_f32_16x16x32_bf16(af[mf][kk], bfrag, acc[mf][nf], 0, 0, 0);
      }
    }
  }
  float bb[4];
#pragma unroll
  for (int nf = 0; nf < 4; ++nf) bb[nf] = bp[n0 + nf * 16 + lr];
#pragma unroll
  for (int mf = 0; mf < 2; ++mf)
#pragma unroll
    for (int nf = 0; nf < 4; ++nf)
#pragma unroll
      for (int r = 0; r < 4; ++r) {
        int m = mrow + mf * 16 + lg * 4 + r;
        int c = n0 + nf * 16 + lr;
        out[m * CEMB + c] = acc[mf][nf][r] + bb[nf];
      }
}

extern "C" void kernel_launch(void* const* d_in, const int* in_sizes, int n_in,
                              void* d_out, int out_size, void* d_ws, size_t ws_size,
                              hipStream_t stream) {
  (void)in_sizes; (void)n_in; (void)out_size; (void)ws_size;
  const float* x  = (const float*)d_in[0];
  // d_in[1] = batch indices (unused: equal-length segments, B=128, T=256)
  const float* Wq = (const float*)d_in[2];
  const float* bq = (const float*)d_in[3];
  const float* Wk = (const float*)d_in[4];
  const float* bk = (const float*)d_in[5];
  const float* Wv = (const float*)d_in[6];
  const float* bv = (const float*)d_in[7];
  const float* Wp = (const float*)d_in[8];
  const float* bp = (const float*)d_in[9];
  float* out = (float*)d_out;

  char* ws = (char*)d_ws;
  u16* xb   = (u16*)(ws);                    // 16 MiB (reused as y_ws after k_qkv)
  u16* wb   = (u16*)(ws + 16777216);         // 512 KiB
  u16* q_ws = (u16*)(ws + 17301504);         // 16 MiB
  u16* k_ws = (u16*)(ws + 34078720);         // 16 MiB
  u16* v_ws = (u16*)(ws + 50855936);         // 16 MiB (transposed [b,h,hd,T])
  u16* y_ws = xb;
  float* mean_out = out + (size_t)NTOK * CEMB;

  k_convert<<<4224, 256, 0, stream>>>(x, Wq, Wk, Wv, Wp, xb, wb);
  k_qkv<<<dim3(256, 4, 3), 256, 0, stream>>>(xb, wb, bq, bk, bv, q_ws, k_ws, v_ws);
  k_attn<<<dim3(16, 128), 256, 0, stream>>>(q_ws, k_ws, v_ws, y_ws, mean_out);
  k_proj<<<dim3(256, 4), 256, 0, stream>>>(y_ws, wb, bp, out);
}

// Round 3
// 170.329 us; speedup vs baseline: 2.1012x; 2.1012x over previous
//
#include <hip/hip_runtime.h>
#include <hip/hip_bf16.h>
#include <stdint.h>

typedef unsigned short u16;
typedef __bf16 bf16_t;
typedef bf16_t bf16x8 __attribute__((ext_vector_type(8)));
typedef float f32x4 __attribute__((ext_vector_type(4)));

#define NTOK 32768
#define CEMB 256
#define NHEAD 8
#define HD 32
#define BSEG 128
#define TSEG 256

static __device__ __forceinline__ bf16x8 ld16(const u16* p) {
  uint4 v = *reinterpret_cast<const uint4*>(p);
  return __builtin_bit_cast(bf16x8, v);
}
static __device__ __forceinline__ u16 f2b(float f) {
  return __builtin_bit_cast(u16, (bf16_t)f);
}

// ---------------- K0: convert x and weights to bf16 ----------------
__global__ void k_convert(const float* __restrict__ x,
                          const float* __restrict__ wq, const float* __restrict__ wk,
                          const float* __restrict__ wv, const float* __restrict__ wp,
                          u16* __restrict__ xb, u16* __restrict__ wb) {
  const int XSLOTS = (NTOK * CEMB) / 8;      // 1048576
  const int WSLOTS = (4 * CEMB * CEMB) / 8;  // 32768
  int slot = blockIdx.x * blockDim.x + threadIdx.x;
  if (slot >= XSLOTS + WSLOTS) return;
  const float* src;
  u16* dst;
  if (slot < XSLOTS) {
    src = x + slot * 8;
    dst = xb + slot * 8;
  } else {
    int e = (slot - XSLOTS) * 8;
    int wsel = e >> 16, off = e & 65535;
    const float* s0 = (wsel == 0) ? wq : ((wsel == 1) ? wk : ((wsel == 2) ? wv : wp));
    src = s0 + off;
    dst = wb + e;
  }
  float4 a = reinterpret_cast<const float4*>(src)[0];
  float4 b = reinterpret_cast<const float4*>(src)[1];
  u16 o[8] = {f2b(a.x), f2b(a.y), f2b(a.z), f2b(a.w),
              f2b(b.x), f2b(b.y), f2b(b.z), f2b(b.w)};
  *reinterpret_cast<uint4*>(dst) = *reinterpret_cast<const uint4*>(o);
}

// ---------------- K1: QKV projection GEMMs ----------------
// 1D grid 3072, XCD-chunked so the 12 blocks (3 modes x 4 n-tiles) sharing an
// A-tile run on the same XCD's L2.
__global__ __launch_bounds__(256, 4)
void k_qkv(const u16* __restrict__ xb, const u16* __restrict__ wb,
           const float* __restrict__ bq, const float* __restrict__ bk,
           const float* __restrict__ bv,
           u16* __restrict__ q_ws, u16* __restrict__ k_ws, u16* __restrict__ v_ws) {
  const int d = blockIdx.x;
  const int xcd = d & 7, i = d >> 3;         // i in 0..383
  const int m_idx = xcd * 32 + i / 12;
  const int rr = i % 12;
  const int mode = rr >> 2;                  // 0..2
  const int n0 = (rr & 3) * 64;
  const int m0 = m_idx * 128;
  const int tid = threadIdx.x;
  const int w = tid >> 6, l = tid & 63;
  const int lr = l & 15, lg = l >> 4;
  __shared__ u16 Ts[64][136];  // V-transpose bounce buffer

  const u16* W = wb + mode * (CEMB * CEMB);
  const float* bias = (mode == 0) ? bq : ((mode == 1) ? bk : bv);

  f32x4 acc[2][4];
#pragma unroll
  for (int mf = 0; mf < 2; ++mf)
#pragma unroll
    for (int nf = 0; nf < 4; ++nf) {
      f32x4 z = {0.f, 0.f, 0.f, 0.f};
      acc[mf][nf] = z;
    }
  const int mrow = m0 + w * 32;

#pragma unroll
  for (int kt = 0; kt < 4; ++kt) {
    bf16x8 af[2][2];
#pragma unroll
    for (int mf = 0; mf < 2; ++mf)
#pragma unroll
      for (int kk = 0; kk < 2; ++kk)
        af[mf][kk] = ld16(xb + (mrow + mf * 16 + lr) * CEMB + kt * 64 + kk * 32 + lg * 8);
#pragma unroll
    for (int nf = 0; nf < 4; ++nf) {
#pragma unroll
      for (int kk = 0; kk < 2; ++kk) {
        bf16x8 bfrag = ld16(W + (n0 + nf * 16 + lr) * CEMB + kt * 64 + kk * 32 + lg * 8);
#pragma unroll
        for (int mf = 0; mf < 2; ++mf)
          acc[mf][nf] = __builtin_amdgcn_mfma_f32_16x16x32_bf16(af[mf][kk], bfrag, acc[mf][nf], 0, 0, 0);
      }
    }
  }

  float bb[4];
#pragma unroll
  for (int nf = 0; nf < 4; ++nf) bb[nf] = bias[n0 + nf * 16 + lr];

  if (mode < 2) {
    u16* out = (mode == 0) ? q_ws : k_ws;
#pragma unroll
    for (int mf = 0; mf < 2; ++mf)
#pragma unroll
      for (int nf = 0; nf < 4; ++nf)
#pragma unroll
        for (int r = 0; r < 4; ++r) {
          int m = mrow + mf * 16 + lg * 4 + r;
          int c = n0 + nf * 16 + lr;
          int bs = m >> 8, t = m & 255, hh = c >> 5, dd = c & 31;
          out[((bs * NHEAD + hh) * TSEG + t) * HD + dd] = f2b(acc[mf][nf][r] + bb[nf]);
        }
  } else {
    // stage into LDS then store V transposed: v_ws[(b*8+h)*32+d][t]
#pragma unroll
    for (int mf = 0; mf < 2; ++mf)
#pragma unroll
      for (int nf = 0; nf < 4; ++nf)
#pragma unroll
        for (int r = 0; r < 4; ++r)
          Ts[nf * 16 + lr][w * 32 + mf * 16 + lg * 4 + r] = f2b(acc[mf][nf][r] + bb[nf]);
    __syncthreads();
    int row = tid >> 2;            // 0..63 : local c
    int seg = (tid & 3) * 32;      // t offset chunk
    int c = n0 + row, hh = c >> 5, dd = c & 31;
    int bs = m0 >> 8, t0 = m0 & 255;
    u16* dst = v_ws + ((bs * NHEAD + hh) * HD + dd) * TSEG + t0 + seg;
#pragma unroll
    for (int j = 0; j < 4; ++j)
      reinterpret_cast<uint4*>(dst)[j] = *reinterpret_cast<const uint4*>(&Ts[row][seg + j * 8]);
  }
}

// ---------------- K2: attention ----------------
// Block = (b, t-half): 8 waves x 16 t-rows, all 8 heads serial per wave.
// S^T = mfma(A=K(permuted rows), B=Q): lane (lr,lg) reg r holds
// P^T[s = 32*(st>>1)+4*(st&1)+8*lg+r][t = tbase+lr] -> PV B-frags are pure
// in-register bf16 packing; head-mean accumulates fully in registers.
__global__ __launch_bounds__(512, 2)
void k_attn(const u16* __restrict__ q_ws, const u16* __restrict__ k_ws,
            const u16* __restrict__ v_ws,
            u16* __restrict__ y_ws, float* __restrict__ mean_out) {
  const int dblk = blockIdx.x;
  const int xcd = dblk & 7, ii = dblk >> 3;  // ii in 0..31
  const int b = xcd * 16 + (ii >> 1);
  const int th = ii & 1;
  const int tid = threadIdx.x;
  const int w = tid >> 6, l = tid & 63;
  const int lr = l & 15, lg = l >> 4;
  const int tbase = th * 128 + w * 16;

  extern __shared__ float smem[];            // per-wave [16t][260s] f32

  float macc[16][4];
#pragma unroll
  for (int st = 0; st < 16; ++st)
#pragma unroll
    for (int r = 0; r < 4; ++r) macc[st][r] = 0.f;

  const float sc = 0.17677669529663687f * 1.4426950408889634f;  // 1/sqrt(32)*log2e
  const int rowperm = 8 * (lr >> 2) + (lr & 3);

  for (int h = 0; h < NHEAD; ++h) {
    const u16* qh = q_ws + (b * NHEAD + h) * TSEG * HD;
    const u16* kh = k_ws + (b * NHEAD + h) * TSEG * HD;
    const u16* vh = v_ws + (b * NHEAD + h) * HD * TSEG;

    bf16x8 qf = ld16(qh + (tbase + lr) * HD + lg * 8);

    float s[16][4];
#pragma unroll
    for (int st = 0; st < 16; ++st) {
      int srow = (st >> 1) * 32 + (st & 1) * 4 + rowperm;
      bf16x8 kf = ld16(kh + srow * HD + lg * 8);
      f32x4 z = {0.f, 0.f, 0.f, 0.f};
      f32x4 dd = __builtin_amdgcn_mfma_f32_16x16x32_bf16(kf, qf, z, 0, 0, 0);
#pragma unroll
      for (int r = 0; r < 4; ++r) s[st][r] = dd[r] * sc;
    }

    float mx = s[0][0];
#pragma unroll
    for (int st = 0; st < 16; ++st)
#pragma unroll
      for (int r = 0; r < 4; ++r) mx = fmaxf(mx, s[st][r]);
    mx = fmaxf(mx, __shfl_xor(mx, 16, 64));
    mx = fmaxf(mx, __shfl_xor(mx, 32, 64));

    float sm = 0.f;
#pragma unroll
    for (int st = 0; st < 16; ++st)
#pragma unroll
      for (int r = 0; r < 4; ++r) {
        float p = exp2f(s[st][r] - mx);
        s[st][r] = p;
        sm += p;
      }
    sm += __shfl_xor(sm, 16, 64);
    sm += __shfl_xor(sm, 32, 64);
    float inv = __builtin_amdgcn_rcpf(sm);

    bf16x8 pb[8];
#pragma unroll
    for (int kk = 0; kk < 8; ++kk)
#pragma unroll
      for (int e = 0; e < 4; ++e) {
        float p0 = s[2 * kk][e] * inv;
        float p1 = s[2 * kk + 1][e] * inv;
        macc[2 * kk][e] += p0;
        macc[2 * kk + 1][e] += p1;
        pb[kk][e] = (bf16_t)p0;
        pb[kk][4 + e] = (bf16_t)p1;
      }

#pragma unroll
    for (int dt = 0; dt < 2; ++dt) {
      f32x4 y = {0.f, 0.f, 0.f, 0.f};
#pragma unroll
      for (int kk = 0; kk < 8; ++kk) {
        bf16x8 vf = ld16(vh + (dt * 16 + lr) * TSEG + kk * 32 + lg * 8);
        y = __builtin_amdgcn_mfma_f32_16x16x32_bf16(vf, pb[kk], y, 0, 0, 0);
      }
      u16 o[4] = {f2b(y[0]), f2b(y[1]), f2b(y[2]), f2b(y[3])};
      *reinterpret_cast<uint2*>(
          y_ws + (size_t)(b * TSEG + tbase + lr) * CEMB + h * HD + dt * 16 + lg * 4) =
          *reinterpret_cast<const uint2*>(o);
    }
  }

  // head-mean: registers -> wave-private LDS tile (transpose) -> coalesced out.
  float* smw = smem + w * (16 * 260);
#pragma unroll
  for (int st = 0; st < 16; ++st) {
    int sb = (st >> 1) * 32 + (st & 1) * 4 + 8 * lg;
#pragma unroll
    for (int r = 0; r < 4; ++r)
      smw[lr * 260 + sb + r] = macc[st][r] * 0.125f;
  }
  // wave-private LDS: no barrier needed (same-wave ds ordering)
  {
    int tl = l >> 2;              // 0..15
    int s0 = (l & 3) * 64;        // s chunk
    float* dst = mean_out + (size_t)(b * TSEG + tbase + tl) * TSEG + s0;
    const float* srcp = smw + tl * 260 + s0;
#pragma unroll
    for (int j = 0; j < 16; ++j)
      *reinterpret_cast<float4*>(dst + 4 * j) =
          *reinterpret_cast<const float4*>(srcp + 4 * j);
  }
}

// ---------------- K3: output projection ----------------
// 1D grid 1024, XCD-chunked: 4 n-tiles sharing an A-tile on one XCD.
__global__ __launch_bounds__(256, 4)
void k_proj(const u16* __restrict__ yb, const u16* __restrict__ wb,
            const float* __restrict__ bp, float* __restrict__ out) {
  const int d = blockIdx.x;
  const int xcd = d & 7, i = d >> 3;         // i in 0..127
  const int m0 = (xcd * 32 + (i >> 2)) * 128;
  const int n0 = (i & 3) * 64;
  const int tid = threadIdx.x;
  const int w = tid >> 6, l = tid & 63;
  const int lr = l & 15, lg = l >> 4;
  const u16* W = wb + 3 * (CEMB * CEMB);

  f32x4 acc[2][4];
#pragma unroll
  for (int mf = 0; mf < 2; ++mf)
#pragma unroll
    for (int nf = 0; nf < 4; ++nf) {
      f32x4 z = {0.f, 0.f, 0.f, 0.f};
      acc[mf][nf] = z;
    }
  const int mrow = m0 + w * 32;

#pragma unroll
  for (int kt = 0; kt < 4; ++kt) {
    bf16x8 af[2][2];
#pragma unroll
    for (int mf = 0; mf < 2; ++mf)
#pragma unroll
      for (int kk = 0; kk < 2; ++kk)
        af[mf][kk] = ld16(yb + (mrow + mf * 16 + lr) * CEMB + kt * 64 + kk * 32 + lg * 8);
#pragma unroll
    for (int nf = 0; nf < 4; ++nf) {
#pragma unroll
      for (int kk = 0; kk < 2; ++kk) {
        bf16x8 bfrag = ld16(W + (n0 + nf * 16 + lr) * CEMB + kt * 64 + kk * 32 + lg * 8);
#pragma unroll
        for (int mf = 0; mf < 2; ++mf)
          acc[mf][nf] = __builtin_amdgcn_mfma_f32_16x16x32_bf16(af[mf][kk], bfrag, acc[mf][nf], 0, 0, 0);
      }
    }
  }
  float bb[4];
#pragma unroll
  for (int nf = 0; nf < 4; ++nf) bb[nf] = bp[n0 + nf * 16 + lr];
#pragma unroll
  for (int mf = 0; mf < 2; ++mf)
#pragma unroll
    for (int nf = 0; nf < 4; ++nf)
#pragma unroll
      for (int r = 0; r < 4; ++r) {
        int m = mrow + mf * 16 + lg * 4 + r;
        int c = n0 + nf * 16 + lr;
        out[m * CEMB + c] = acc[mf][nf][r] + bb[nf];
      }
}

extern "C" void kernel_launch(void* const* d_in, const int* in_sizes, int n_in,
                              void* d_out, int out_size, void* d_ws, size_t ws_size,
                              hipStream_t stream) {
  (void)in_sizes; (void)n_in; (void)out_size; (void)ws_size;
  const float* x  = (const float*)d_in[0];
  // d_in[1] = batch indices (unused: equal-length segments, B=128, T=256)
  const float* Wq = (const float*)d_in[2];
  const float* bq = (const float*)d_in[3];
  const float* Wk = (const float*)d_in[4];
  const float* bk = (const float*)d_in[5];
  const float* Wv = (const float*)d_in[6];
  const float* bv = (const float*)d_in[7];
  const float* Wp = (const float*)d_in[8];
  const float* bp = (const float*)d_in[9];
  float* out = (float*)d_out;

  char* ws = (char*)d_ws;
  u16* xb   = (u16*)(ws);                    // 16 MiB (reused as y_ws after k_qkv)
  u16* wb   = (u16*)(ws + 16777216);         // 512 KiB
  u16* q_ws = (u16*)(ws + 17301504);         // 16 MiB
  u16* k_ws = (u16*)(ws + 34078720);         // 16 MiB
  u16* v_ws = (u16*)(ws + 50855936);         // 16 MiB (transposed [b,h,hd,T])
  u16* y_ws = xb;
  float* mean_out = out + (size_t)NTOK * CEMB;

  k_convert<<<4224, 256, 0, stream>>>(x, Wq, Wk, Wv, Wp, xb, wb);
  k_qkv<<<3072, 256, 0, stream>>>(xb, wb, bq, bk, bv, q_ws, k_ws, v_ws);
  k_attn<<<256, 512, 8 * 16 * 260 * 4, stream>>>(q_ws, k_ws, v_ws, y_ws, mean_out);
  k_proj<<<1024, 256, 0, stream>>>(y_ws, wb, bp, out);
}

// Round 4
// 127.173 us; speedup vs baseline: 2.8142x; 1.3394x over previous
//
#include <hip/hip_runtime.h>
#include <hip/hip_bf16.h>
#include <stdint.h>

typedef unsigned short u16;
typedef __bf16 bf16_t;
typedef bf16_t bf16x8 __attribute__((ext_vector_type(8)));
typedef float f32x4 __attribute__((ext_vector_type(4)));

#define NTOK 32768
#define CEMB 256
#define NHEAD 8
#define HD 32
#define BSEG 128
#define TSEG 256

static __device__ __forceinline__ bf16x8 ld16(const u16* p) {
  uint4 v = *reinterpret_cast<const uint4*>(p);
  return __builtin_bit_cast(bf16x8, v);
}
static __device__ __forceinline__ u16 f2b(float f) {
  return __builtin_bit_cast(u16, (bf16_t)f);
}

typedef __attribute__((address_space(1))) const void GASV;
typedef __attribute__((address_space(3))) void LASV;
static __device__ __forceinline__ void stage16(const u16* g, u16* l) {
  __builtin_amdgcn_global_load_lds((GASV*)g, (LASV*)l, 16, 0, 0);
}

// ---------------- K0: convert x and weights to bf16 ----------------
__global__ void k_convert(const float* __restrict__ x,
                          const float* __restrict__ wq, const float* __restrict__ wk,
                          const float* __restrict__ wv, const float* __restrict__ wp,
                          u16* __restrict__ xb, u16* __restrict__ wb) {
  const int XSLOTS = (NTOK * CEMB) / 8;      // 1048576
  const int WSLOTS = (4 * CEMB * CEMB) / 8;  // 32768
  int slot = blockIdx.x * blockDim.x + threadIdx.x;
  if (slot >= XSLOTS + WSLOTS) return;
  const float* src;
  u16* dst;
  if (slot < XSLOTS) {
    src = x + slot * 8;
    dst = xb + slot * 8;
  } else {
    int e = (slot - XSLOTS) * 8;
    int wsel = e >> 16, off = e & 65535;
    const float* s0 = (wsel == 0) ? wq : ((wsel == 1) ? wk : ((wsel == 2) ? wv : wp));
    src = s0 + off;
    dst = wb + e;
  }
  float4 a = reinterpret_cast<const float4*>(src)[0];
  float4 b = reinterpret_cast<const float4*>(src)[1];
  u16 o[8] = {f2b(a.x), f2b(a.y), f2b(a.z), f2b(a.w),
              f2b(b.x), f2b(b.y), f2b(b.z), f2b(b.w)};
  *reinterpret_cast<uint4*>(dst) = *reinterpret_cast<const uint4*>(o);
}

// ======== shared GEMM core pieces (BM=128, BN=128, BK=64, 4 waves 2x2) ========
// LDS: As dbuf [2][128][64] + Bs dbuf [2][128][64] bf16 = 64 KB; epilogue
// reuses first 32 KB as a 128x128 u16 bounce tile. Staging uses
// global_load_lds(16B) with inverse-swizzled SOURCE; ds_read applies the
// same XOR swizzle (byte ^= (row&7)<<4) -> conflict-free b128 reads.

#define GEMM_MAIN_LOOP(Asrc, Bsrc)                                              \
  f32x4 acc[4][4];                                                              \
  _Pragma("unroll") for (int mf = 0; mf < 4; ++mf)                              \
      _Pragma("unroll") for (int nf = 0; nf < 4; ++nf) {                        \
    f32x4 z = {0.f, 0.f, 0.f, 0.f};                                             \
    acc[mf][nf] = z;                                                            \
  }                                                                             \
  u16* As = lds;                                                                \
  u16* Bs = lds + 16384;                                                        \
  auto STAGE = [&](int buf, int kt) {                                           \
    _Pragma("unroll") for (int i = 0; i < 4; ++i) {                             \
      int cidx = i * 256 + tid;                                                 \
      int row = cidx >> 3;                                                      \
      int scb = ((cidx & 7) << 4) ^ ((row & 7) << 4); /* src col bytes */       \
      u16* dst_lds = As + buf * 8192 + (i * 256 + w * 64) * 8;                  \
      stage16(Asrc + (size_t)(m0 + row) * CEMB + kt * 64 + (scb >> 1), dst_lds);\
      u16* dst_ldsb = Bs + buf * 8192 + (i * 256 + w * 64) * 8;                 \
      stage16(Bsrc + (size_t)(n0 + row) * CEMB + kt * 64 + (scb >> 1), dst_ldsb);\
    }                                                                           \
  };                                                                            \
  STAGE(0, 0);                                                                  \
  __syncthreads();                                                              \
  for (int kt = 0; kt < 4; ++kt) {                                              \
    int buf = kt & 1;                                                           \
    if (kt < 3) STAGE(buf ^ 1, kt + 1);                                         \
    bf16x8 av[4][2], bw[4][2];                                                  \
    _Pragma("unroll") for (int mf = 0; mf < 4; ++mf)                            \
        _Pragma("unroll") for (int kk = 0; kk < 2; ++kk) {                      \
      int row = wr * 64 + mf * 16 + lr;                                         \
      int byte = row * 128 + ((kk * 64 + lg * 16) ^ ((row & 7) << 4));          \
      av[mf][kk] = *reinterpret_cast<const bf16x8*>(                            \
          (const char*)(As + buf * 8192) + byte);                               \
    }                                                                           \
    _Pragma("unroll") for (int nf = 0; nf < 4; ++nf)                            \
        _Pragma("unroll") for (int kk = 0; kk < 2; ++kk) {                      \
      int row = wc * 64 + nf * 16 + lr;                                         \
      int byte = row * 128 + ((kk * 64 + lg * 16) ^ ((row & 7) << 4));          \
      bw[nf][kk] = *reinterpret_cast<const bf16x8*>(                            \
          (const char*)(Bs + buf * 8192) + byte);                               \
    }                                                                           \
    _Pragma("unroll") for (int kk = 0; kk < 2; ++kk)                            \
        _Pragma("unroll") for (int nf = 0; nf < 4; ++nf)                        \
            _Pragma("unroll") for (int mf = 0; mf < 4; ++mf)                    \
      acc[mf][nf] = __builtin_amdgcn_mfma_f32_16x16x32_bf16(                    \
          av[mf][kk], bw[nf][kk], acc[mf][nf], 0, 0, 0);                        \
    __syncthreads();                                                            \
  }

// ---------------- K1: QKV projection GEMMs ----------------
// grid 1536 XCD-chunked: per XCD contiguous m-range; 6 blocks/m-tile
// (3 modes x 2 n-halves) share the A panel in that XCD's L2.
__global__ __launch_bounds__(256, 2)
void k_qkv(const u16* __restrict__ xb, const u16* __restrict__ wb,
           const float* __restrict__ bq, const float* __restrict__ bk,
           const float* __restrict__ bv,
           u16* __restrict__ q_ws, u16* __restrict__ k_ws, u16* __restrict__ v_ws) {
  const int d = blockIdx.x;
  const int xcd = d & 7, i = d >> 3;          // i in 0..191
  const int m_idx = xcd * 32 + i / 6;         // 0..255
  const int rr = i % 6;
  const int mode = rr >> 1;                   // 0=Q,1=K,2=V
  const int n0 = (rr & 1) * 128;
  const int m0 = m_idx * 128;
  const int tid = threadIdx.x;
  const int w = tid >> 6, l = tid & 63;
  const int lr = l & 15, lg = l >> 4;
  const int wr = w >> 1, wc = w & 1;

  __shared__ u16 lds[32768];  // 64 KB

  const u16* W = wb + mode * (CEMB * CEMB);
  const float* bias = (mode == 0) ? bq : ((mode == 1) ? bk : bv);

  GEMM_MAIN_LOOP(xb, W)

  float bb[4];
#pragma unroll
  for (int nf = 0; nf < 4; ++nf) bb[nf] = bias[n0 + wc * 64 + nf * 16 + lr];

  if (mode < 2) {
    // bounce via LDS -> plain [m][256] bf16 layout, coalesced 16B stores
    u16* Et = lds;
#pragma unroll
    for (int mf = 0; mf < 4; ++mf)
#pragma unroll
      for (int nf = 0; nf < 4; ++nf)
#pragma unroll
        for (int r = 0; r < 4; ++r) {
          int row = wr * 64 + mf * 16 + lg * 4 + r;
          int col = wc * 64 + nf * 16 + lr;
          int byte = (row * 256 + col * 2) ^ ((row & 7) << 4);
          *(u16*)((char*)Et + byte) = f2b(acc[mf][nf][r] + bb[nf]);
        }
    __syncthreads();
    u16* out = (mode == 0) ? q_ws : k_ws;
    int row_l = tid >> 1, half = tid & 1;
    u16* dstp = out + (size_t)(m0 + row_l) * CEMB + n0 + half * 64;
#pragma unroll
    for (int j = 0; j < 8; ++j) {
      int byte = row_l * 256 + (((half * 64 + j * 8) * 2) ^ ((row_l & 7) << 4));
      *reinterpret_cast<uint4*>(dstp + j * 8) =
          *reinterpret_cast<const uint4*>((const char*)Et + byte);
    }
  } else {
    // V: bounce transposed -> v_ws[b,h,d,t], coalesced 16B stores
    u16* Vt = lds;
#pragma unroll
    for (int mf = 0; mf < 4; ++mf)
#pragma unroll
      for (int nf = 0; nf < 4; ++nf)
#pragma unroll
        for (int r = 0; r < 4; ++r) {
          int row = wr * 64 + mf * 16 + lg * 4 + r;
          int col = wc * 64 + nf * 16 + lr;
          int byte = (col * 256 + row * 2) ^ ((col & 7) << 4);
          *(u16*)((char*)Vt + byte) = f2b(acc[mf][nf][r] + bb[nf]);
        }
    __syncthreads();
    int col_l = tid >> 1, half = tid & 1;
    int c = n0 + col_l, hh = c >> 5, dd = c & 31;
    int bs = m0 >> 8, t0 = m0 & 255;
    u16* dst = v_ws + ((size_t)(bs * NHEAD + hh) * HD + dd) * TSEG + t0 + half * 64;
#pragma unroll
    for (int j = 0; j < 8; ++j) {
      int byte = col_l * 256 + ((half * 128 + j * 16) ^ ((col_l & 7) << 4));
      *reinterpret_cast<uint4*>(dst + j * 8) =
          *reinterpret_cast<const uint4*>((const char*)Vt + byte);
    }
  }
}

// ---------------- K2: attention ----------------
// Block = (b, t-half): 8 waves x 16 t-rows, all 8 heads serial per wave.
// Q/K now in plain [m][256] layout (column block h*32 per head).
__global__ __launch_bounds__(512, 2)
void k_attn(const u16* __restrict__ q_ws, const u16* __restrict__ k_ws,
            const u16* __restrict__ v_ws,
            u16* __restrict__ y_ws, float* __restrict__ mean_out) {
  const int dblk = blockIdx.x;
  const int xcd = dblk & 7, ii = dblk >> 3;  // ii in 0..31
  const int b = xcd * 16 + (ii >> 1);
  const int th = ii & 1;
  const int tid = threadIdx.x;
  const int w = tid >> 6, l = tid & 63;
  const int lr = l & 15, lg = l >> 4;
  const int tbase = th * 128 + w * 16;

  extern __shared__ float smem[];            // per-wave [16t][260s] f32

  float macc[16][4];
#pragma unroll
  for (int st = 0; st < 16; ++st)
#pragma unroll
    for (int r = 0; r < 4; ++r) macc[st][r] = 0.f;

  const float sc = 0.17677669529663687f * 1.4426950408889634f;  // 1/sqrt(32)*log2e
  const int rowperm = 8 * (lr >> 2) + (lr & 3);

  const u16* qseg = q_ws + (size_t)b * TSEG * CEMB;
  const u16* kseg = k_ws + (size_t)b * TSEG * CEMB;

  for (int h = 0; h < NHEAD; ++h) {
    const u16* qh = qseg + h * HD;
    const u16* kh = kseg + h * HD;
    const u16* vh = v_ws + (b * NHEAD + h) * HD * TSEG;

    bf16x8 qf = ld16(qh + (tbase + lr) * CEMB + lg * 8);

    float s[16][4];
#pragma unroll
    for (int st = 0; st < 16; ++st) {
      int srow = (st >> 1) * 32 + (st & 1) * 4 + rowperm;
      bf16x8 kf = ld16(kh + srow * CEMB + lg * 8);
      f32x4 z = {0.f, 0.f, 0.f, 0.f};
      f32x4 dd = __builtin_amdgcn_mfma_f32_16x16x32_bf16(kf, qf, z, 0, 0, 0);
#pragma unroll
      for (int r = 0; r < 4; ++r) s[st][r] = dd[r] * sc;
    }

    float mx = s[0][0];
#pragma unroll
    for (int st = 0; st < 16; ++st)
#pragma unroll
      for (int r = 0; r < 4; ++r) mx = fmaxf(mx, s[st][r]);
    mx = fmaxf(mx, __shfl_xor(mx, 16, 64));
    mx = fmaxf(mx, __shfl_xor(mx, 32, 64));

    float sm = 0.f;
#pragma unroll
    for (int st = 0; st < 16; ++st)
#pragma unroll
      for (int r = 0; r < 4; ++r) {
        float p = exp2f(s[st][r] - mx);
        s[st][r] = p;
        sm += p;
      }
    sm += __shfl_xor(sm, 16, 64);
    sm += __shfl_xor(sm, 32, 64);
    float inv = __builtin_amdgcn_rcpf(sm);

    bf16x8 pb[8];
#pragma unroll
    for (int kk = 0; kk < 8; ++kk)
#pragma unroll
      for (int e = 0; e < 4; ++e) {
        float p0 = s[2 * kk][e] * inv;
        float p1 = s[2 * kk + 1][e] * inv;
        macc[2 * kk][e] += p0;
        macc[2 * kk + 1][e] += p1;
        pb[kk][e] = (bf16_t)p0;
        pb[kk][4 + e] = (bf16_t)p1;
      }

#pragma unroll
    for (int dt = 0; dt < 2; ++dt) {
      f32x4 y = {0.f, 0.f, 0.f, 0.f};
#pragma unroll
      for (int kk = 0; kk < 8; ++kk) {
        bf16x8 vf = ld16(vh + (dt * 16 + lr) * TSEG + kk * 32 + lg * 8);
        y = __builtin_amdgcn_mfma_f32_16x16x32_bf16(vf, pb[kk], y, 0, 0, 0);
      }
      u16 o[4] = {f2b(y[0]), f2b(y[1]), f2b(y[2]), f2b(y[3])};
      *reinterpret_cast<uint2*>(
          y_ws + (size_t)(b * TSEG + tbase + lr) * CEMB + h * HD + dt * 16 + lg * 4) =
          *reinterpret_cast<const uint2*>(o);
    }
  }

  // head-mean: registers -> wave-private LDS tile (transpose) -> coalesced out.
  float* smw = smem + w * (16 * 260);
#pragma unroll
  for (int st = 0; st < 16; ++st) {
    int sb = (st >> 1) * 32 + (st & 1) * 4 + 8 * lg;
#pragma unroll
    for (int r = 0; r < 4; ++r)
      smw[lr * 260 + sb + r] = macc[st][r] * 0.125f;
  }
  {
    int tl = l >> 2;              // 0..15
    int s0 = (l & 3) * 64;        // s chunk
    float* dst = mean_out + (size_t)(b * TSEG + tbase + tl) * TSEG + s0;
    const float* srcp = smw + tl * 260 + s0;
#pragma unroll
    for (int j = 0; j < 16; ++j)
      *reinterpret_cast<float4*>(dst + 4 * j) =
          *reinterpret_cast<const float4*>(srcp + 4 * j);
  }
}

// ---------------- K3: output projection ----------------
__global__ __launch_bounds__(256, 2)
void k_proj(const u16* __restrict__ yb, const u16* __restrict__ wb,
            const float* __restrict__ bp, float* __restrict__ out) {
  const int d = blockIdx.x;
  const int xcd = d & 7, i = d >> 3;          // i in 0..63
  const int m0 = (xcd * 32 + (i >> 1)) * 128;
  const int n0 = (i & 1) * 128;
  const int tid = threadIdx.x;
  const int w = tid >> 6, l = tid & 63;
  const int lr = l & 15, lg = l >> 4;
  const int wr = w >> 1, wc = w & 1;
  const u16* W = wb + 3 * (CEMB * CEMB);

  __shared__ u16 lds[32768];  // 64 KB

  GEMM_MAIN_LOOP(yb, W)

  float bb[4];
#pragma unroll
  for (int nf = 0; nf < 4; ++nf) bb[nf] = bp[n0 + wc * 64 + nf * 16 + lr];
#pragma unroll
  for (int mf = 0; mf < 4; ++mf)
#pragma unroll
    for (int nf = 0; nf < 4; ++nf)
#pragma unroll
      for (int r = 0; r < 4; ++r) {
        int m = m0 + wr * 64 + mf * 16 + lg * 4 + r;
        int c = n0 + wc * 64 + nf * 16 + lr;
        out[(size_t)m * CEMB + c] = acc[mf][nf][r] + bb[nf];
      }
}

extern "C" void kernel_launch(void* const* d_in, const int* in_sizes, int n_in,
                              void* d_out, int out_size, void* d_ws, size_t ws_size,
                              hipStream_t stream) {
  (void)in_sizes; (void)n_in; (void)out_size; (void)ws_size;
  const float* x  = (const float*)d_in[0];
  // d_in[1] = batch indices (unused: equal-length segments, B=128, T=256)
  const float* Wq = (const float*)d_in[2];
  const float* bq = (const float*)d_in[3];
  const float* Wk = (const float*)d_in[4];
  const float* bk = (const float*)d_in[5];
  const float* Wv = (const float*)d_in[6];
  const float* bv = (const float*)d_in[7];
  const float* Wp = (const float*)d_in[8];
  const float* bp = (const float*)d_in[9];
  float* out = (float*)d_out;

  char* ws = (char*)d_ws;
  u16* xb   = (u16*)(ws);                    // 16 MiB (reused as y_ws after k_qkv)
  u16* wb   = (u16*)(ws + 16777216);         // 512 KiB
  u16* q_ws = (u16*)(ws + 17301504);         // 16 MiB, plain [m][256]
  u16* k_ws = (u16*)(ws + 34078720);         // 16 MiB, plain [m][256]
  u16* v_ws = (u16*)(ws + 50855936);         // 16 MiB, transposed [b,h,d,t]
  u16* y_ws = xb;
  float* mean_out = out + (size_t)NTOK * CEMB;

  k_convert<<<4224, 256, 0, stream>>>(x, Wq, Wk, Wv, Wp, xb, wb);
  k_qkv<<<1536, 256, 0, stream>>>(xb, wb, bq, bk, bv, q_ws, k_ws, v_ws);
  k_attn<<<256, 512, 8 * 16 * 260 * 4, stream>>>(q_ws, k_ws, v_ws, y_ws, mean_out);
  k_proj<<<512, 256, 0, stream>>>(y_ws, wb, bp, out);
}